// Round 4
// baseline (1390.879 us; speedup 1.0000x reference)
//
#include <hip/hip_runtime.h>

// Fused SIREN INR round 4. Round-3 structure (TOK=128, 8 waves of 64feat x
// 128tok, chunk-major LDS h[chunk=f>>3][tok][8]) + software pipeline over
// TOKEN HALVES: per layer,
//   gemm_A(l) | bar | epi_A(l) || gemm_B(l) | bar | epi_B(l) || gemm_A(l+1)...
// Epilogue units (4 sines + ds_write_b64) are interleaved into the k-loop of
// the other half's GEMM, so the sin/cvt VALU work issues under the MFMA
// shadow and no barrier interval is MFMA-dead. Token halves are LDS-address
// disjoint -> one barrier per slot is sufficient. Both acc arrays (2x64 f32)
// live simultaneously -> AGPR file (as round 3's 128).

#define L_TOTAL 262144
#define TOK 128
#define THREADS 512
#define C_SC 4.77464829275686f  // 30/(2*pi)

typedef _Float16 f16x8 __attribute__((ext_vector_type(8)));
typedef _Float16 f16x4 __attribute__((ext_vector_type(4)));
typedef float    f32x4 __attribute__((ext_vector_type(4)));

#define N1 (512 * 256)                 // W_first elems
#define N2 (N1 + 5 * 512 * 512)        // + W_hidden
#define N3 (N2 + 16 * 512)             // + W_out padded to 16 rows
#define NBIAS 3072                     // 512 first + 5*512 hidden (pre-scaled)

__global__ void convert_weights(const float* __restrict__ Wf,
                                const float* __restrict__ Wh,
                                const float* __restrict__ Wo,
                                const float* __restrict__ bf,
                                const float* __restrict__ bh,
                                _Float16* __restrict__ o,
                                float* __restrict__ biasC) {
  int i = blockIdx.x * blockDim.x + threadIdx.x;
  if (i < N3) {
    float v;
    if (i < N1) {
      v = Wf[i];
    } else if (i < N2) {
      v = Wh[i - N1];
    } else {
      int r = (i - N2) >> 9, c = (i - N2) & 511;
      v = (r < 3) ? Wo[r * 512 + c] : 0.0f;
    }
    o[i] = (_Float16)v;
  } else if (i < N3 + NBIAS) {
    int j = i - N3;
    biasC[j] = (j < 512 ? bf[j] : bh[j - 512]) * C_SC;
  }
}

// h buffer LDS layout: elem addr = (chunk*128 + token)*8 + (f&7), chunk=f>>3.
__device__ __forceinline__ int h_elem(int chunk, int token) {
  return (chunk * 128 + token) * 8;
}

// One pipeline slot: optionally GEMM token-half `half` of this layer into
// `acc`, interleaved with the epilogue of `accE` (other half `halfE`,
// previous slot's pre-activations) written back into hb.
template <int K, bool GEMM, bool EPI>
__device__ __forceinline__ void slot(const _Float16* __restrict__ W,
                                     _Float16* hb, f32x4 (&acc)[4][4],
                                     int half, f32x4 (&accE)[4][4],
                                     const float* __restrict__ biasE,
                                     int halfE, int lr, int lg, int m0) {
  constexpr int KS = GEMM ? (K / 32) : 16;
  constexpr int EPB = 16 / KS;  // epilogue units per k-step

  f32x4 bb[4];
  if (EPI) {
#pragma unroll
    for (int mt = 0; mt < 4; ++mt)
      bb[mt] = *(const f32x4*)&biasE[m0 + mt * 16 + lg * 4];
  }

  const _Float16* wrow[4];
  f16x8 a[2][4], b[4];
  if (GEMM) {
#pragma unroll
    for (int mt = 0; mt < 4; ++mt) {
#pragma unroll
      for (int nt = 0; nt < 4; ++nt) acc[mt][nt] = (f32x4){0.f, 0.f, 0.f, 0.f};
      wrow[mt] = &W[(m0 + mt * 16 + lr) * K + lg * 8];
      a[0][mt] = *(const f16x8*)(wrow[mt]);
    }
  }

#pragma unroll
  for (int ks = 0; ks < KS; ++ks) {
    if (GEMM) {
      const int cur = ks & 1;
      // b-frags: addr16B = (ks*4+lg)*128 + token, linear in lr -> no conflict
#pragma unroll
      for (int nt = 0; nt < 4; ++nt)
        b[nt] = *(const f16x8*)&hb[h_elem(ks * 4 + lg, half * 64 + nt * 16 + lr)];
      if (ks + 1 < KS) {  // prefetch next k-step's weight frags
#pragma unroll
        for (int mt = 0; mt < 4; ++mt)
          a[cur ^ 1][mt] = *(const f16x8*)(wrow[mt] + (ks + 1) * 32);
      }
#pragma unroll
      for (int mt = 0; mt < 4; ++mt)
#pragma unroll
        for (int nt = 0; nt < 4; ++nt)
          acc[mt][nt] = __builtin_amdgcn_mfma_f32_16x16x32_f16(
              a[cur][mt], b[nt], acc[mt][nt], 0, 0, 0);
    }
    if (EPI) {
#pragma unroll
      for (int u = 0; u < EPB; ++u) {
        const int e = ks * EPB + u;
        const int mt = e >> 2, nt = e & 3;
        f16x4 hv;
#pragma unroll
        for (int r = 0; r < 4; ++r) {
          float pre = fmaf(accE[mt][nt][r], C_SC, bb[mt][r]);  // revolutions
          hv[r] = (_Float16)__builtin_amdgcn_sinf(__builtin_amdgcn_fractf(pre));
        }
        const int ob = m0 + mt * 16 + lg * 4;
        *(f16x4*)&hb[(ob >> 3) * 1024 + (halfE * 64 + nt * 16 + lr) * 8 +
                     (ob & 7)] = hv;
      }
    }
  }
}

__global__ __launch_bounds__(THREADS, 2) void siren_kernel(
    const float* __restrict__ coords, const float* __restrict__ bff,
    const float* __restrict__ biasC, const float* __restrict__ b_out,
    const _Float16* __restrict__ wf, const _Float16* __restrict__ wh,
    const _Float16* __restrict__ wo, float* __restrict__ out) {
  extern __shared__ _Float16 hb[];  // chunk-major: [64 chunks][128 tok][8]
  const int tid = threadIdx.x;
  const int t0 = blockIdx.x * TOK;

  // ---- Fourier features: chunks q*4+cb (sin), 16+q*4+cb (cos) ----
  {
    const int t = tid & 127;   // token (wave = 64 consecutive tokens)
    const int q = tid >> 7;    // feature octant: proj j in [q*32, q*32+32)
    const float c0 = coords[(t0 + t) * 3 + 0];
    const float c1 = coords[(t0 + t) * 3 + 1];
    const float c2 = coords[(t0 + t) * 3 + 2];
#pragma unroll
    for (int cb = 0; cb < 4; ++cb) {
      f16x8 sv, cv;
#pragma unroll
      for (int e = 0; e < 8; ++e) {
        const int j = q * 32 + cb * 8 + e;
        float r = fmaf(c0, bff[j], fmaf(c1, bff[128 + j], c2 * bff[256 + j]));
        float fr = __builtin_amdgcn_fractf(r);
        sv[e] = (_Float16)__builtin_amdgcn_sinf(fr);
        cv[e] = (_Float16)__builtin_amdgcn_cosf(fr);
      }
      *(f16x8*)&hb[h_elem(q * 4 + cb, t)] = sv;        // lane-linear store
      *(f16x8*)&hb[h_elem(16 + q * 4 + cb, t)] = cv;
    }
  }
  __syncthreads();

  const int lane = tid & 63;
  const int lr = lane & 15;   // A: weight row / B: token / C: token col
  const int lg = lane >> 4;   // k-group for frags, row-group for C
  const int m0 = (tid >> 6) * 64;  // wave's 64-feature output slice

  f32x4 accA[4][4], accB[4][4];

  // ---- pipeline ----
  // fill: gemm_A(L0)
  slot<256, true, false>(wf, hb, accA, 0, accB, biasC, 0, lr, lg, m0);
  __syncthreads();
  // epi_A(L0) || gemm_B(L0)
  slot<256, true, true>(wf, hb, accB, 1, accA, biasC, 0, lr, lg, m0);
  __syncthreads();

  const float* pb = biasC;  // bias of the layer whose half-B epi is pending
#pragma unroll 1
  for (int l = 0; l < 5; ++l) {
    const _Float16* W = wh + l * (512 * 512);
    const float* bl = biasC + 512 + l * 512;
    // epi_B(prev) || gemm_A(Hl)
    slot<512, true, true>(W, hb, accA, 0, accB, pb, 1, lr, lg, m0);
    __syncthreads();
    // epi_A(Hl) || gemm_B(Hl)
    slot<512, true, true>(W, hb, accB, 1, accA, bl, 0, lr, lg, m0);
    __syncthreads();
    pb = bl;
  }
  // drain: epi_B(H4)
  slot<512, false, true>(wf, hb, accA, 0, accB, pb, 1, lr, lg, m0);
  __syncthreads();

  // ---- final linear: out[t][0..2], 16 tokens per wave, 8 waves ----
  {
    const int wave = tid >> 6;
    f32x4 acc = {0.f, 0.f, 0.f, 0.f};
#pragma unroll
    for (int ks = 0; ks < 16; ++ks) {
      f16x8 a = *(const f16x8*)&wo[lr * 512 + ks * 32 + lg * 8];
      f16x8 b = *(const f16x8*)&hb[h_elem(ks * 4 + lg, wave * 16 + lr)];
      acc = __builtin_amdgcn_mfma_f32_16x16x32_f16(a, b, acc, 0, 0, 0);
    }
    if (lg == 0) {  // C rows 0..3 in lanes 0..15; out-feature = reg idx
      const int t = t0 + wave * 16 + lr;
      out[t * 3 + 0] = acc[0] + b_out[0];
      out[t * 3 + 1] = acc[1] + b_out[1];
      out[t * 3 + 2] = acc[2] + b_out[2];
    }
  }
}

extern "C" void kernel_launch(void* const* d_in, const int* in_sizes, int n_in,
                              void* d_out, int out_size, void* d_ws,
                              size_t ws_size, hipStream_t stream) {
  const float* coords = (const float*)d_in[0];
  const float* bff    = (const float*)d_in[1];
  const float* Wf     = (const float*)d_in[2];
  const float* bf     = (const float*)d_in[3];
  const float* Wh     = (const float*)d_in[4];
  const float* bh     = (const float*)d_in[5];
  const float* Wo     = (const float*)d_in[6];
  const float* bo     = (const float*)d_in[7];
  float* out = (float*)d_out;

  _Float16* w16 = (_Float16*)d_ws;
  float* biasC = (float*)(w16 + N3);  // 16B-aligned (N3*2 % 16 == 0)

  convert_weights<<<(N3 + NBIAS + 255) / 256, 256, 0, stream>>>(
      Wf, Wh, Wo, bf, bh, w16, biasC);

  const size_t lds_bytes = 64 * 128 * 8 * sizeof(_Float16);  // 131072
  siren_kernel<<<L_TOTAL / TOK, THREADS, lds_bytes, stream>>>(
      coords, bff, biasC, bo, w16, w16 + N1, w16 + N2, out);
}